// Round 10
// baseline (387.716 us; speedup 1.0000x reference)
//
#include <hip/hip_runtime.h>
#include <hip/hip_bf16.h>
#include <math.h>

// Problem constants
#define TSEQ   2048
#define HID    4096
#define NH     32
#define NKV    8
#define HD     128
#define QKVN   6144              // NH*HD + 2*NKV*HD
#define GSCALE 0.08838834764831845f   // HD^-0.5
#define LOG_THETA 13.122363377404328f // ln(500000)

typedef __bf16 bf16_t;
typedef __attribute__((ext_vector_type(8))) __bf16 bf16x8;
typedef __attribute__((ext_vector_type(4))) float f32x4;

// async global->LDS, 16B per lane; LDS dest is wave-uniform base + lane*16
#define GLOAD_LDS16(gp, lp)                                                    \
  __builtin_amdgcn_global_load_lds(                                            \
      (const __attribute__((address_space(1))) void*)(gp),                     \
      (__attribute__((address_space(3))) void*)(lp), 16, 0, 0)

// ---------------- f32 -> bf16 elementwise convert ----------------
__global__ __launch_bounds__(256) void k_f32_to_bf16(const float* __restrict__ in,
                                                     bf16_t* __restrict__ out, int n) {
  int i = (blockIdx.x * 256 + threadIdx.x) * 4;
  if (i >= n) return;
  float4 v = *(const float4*)(in + i);
  bf16_t o0 = (bf16_t)v.x, o1 = (bf16_t)v.y, o2 = (bf16_t)v.z, o3 = (bf16_t)v.w;
  typedef __attribute__((ext_vector_type(4))) __bf16 bf16x4;
  bf16x4 o = {o0, o1, o2, o3};
  *(bf16x4*)(out + i) = o;
}

// ---------------- out += part1 (f32, float4) ----------------
__global__ __launch_bounds__(256) void k_addout(float* __restrict__ out,
                                                const float* __restrict__ p1, int n4) {
  int i = blockIdx.x * 256 + threadIdx.x;
  if (i >= n4) return;
  float4 a = *(const float4*)(out + i * 4);
  float4 b = *(const float4*)(p1 + i * 4);
  a.x += b.x; a.y += b.y; a.z += b.z; a.w += b.w;
  *(float4*)(out + i * 4) = a;
}

// ---------------- f32 [R][C] -> bf16 [C][R] transpose-convert ----------------
__global__ __launch_bounds__(256) void k_transpose_f32_bf16(const float* __restrict__ in,
                                                            bf16_t* __restrict__ out,
                                                            int R, int C) {
  __shared__ float tile[32][33];
  int tx = threadIdx.x & 31, ty = threadIdx.x >> 5;
  int c0 = blockIdx.x * 32, r0 = blockIdx.y * 32;
#pragma unroll
  for (int i = 0; i < 4; i++)
    tile[ty + i * 8][tx] = in[(size_t)(r0 + ty + i * 8) * C + c0 + tx];
  __syncthreads();
#pragma unroll
  for (int i = 0; i < 4; i++)
    out[(size_t)(c0 + ty + i * 8) * R + r0 + tx] = (bf16_t)tile[tx][ty + i * 8];
}

// ---------------- RoPE (interleaved) in-place on qkv; folds GSCALE into q ----------------
__global__ __launch_bounds__(256) void k_rope(bf16_t* __restrict__ qkv,
                                              const int* __restrict__ positions) {
  int idx = blockIdx.x * 256 + threadIdx.x;   // 0..2559 = 40 heads * 64 pairs
  int t = blockIdx.y;
  int i = idx & 63;          // pair index 0..63
  int hh = idx >> 6;         // 0..39 (0..31 = q heads, 32..39 = k heads)
  if (hh >= 40) return;
  int col = (hh < 32) ? (hh * 128 + 2 * i) : (4096 + (hh - 32) * 128 + 2 * i);
  size_t base = (size_t)t * QKVN + col;
  float x1 = (float)qkv[base];
  float x2 = (float)qkv[base + 1];
  float p = (float)positions[t];
  float inv = expf(-(float)i * (LOG_THETA / 64.0f));
  float ang = p * inv;
  float s, c;
  sincosf(ang, &s, &c);
  float o1 = x1 * c - x2 * s;
  float o2 = x2 * c + x1 * s;
  float sc = (hh < 32) ? GSCALE : 1.0f;
  qkv[base]     = (bf16_t)(o1 * sc);
  qkv[base + 1] = (bf16_t)(o2 * sc);
}

// ---------------- transpose V: qkv[:, 5120+c] (T x 1024) -> vT [1024][T] ----------------
__global__ __launch_bounds__(256) void k_transpose_v(const bf16_t* __restrict__ qkv,
                                                     bf16_t* __restrict__ vT) {
  __shared__ bf16_t tile[32][33];
  int tx = threadIdx.x & 31, ty = threadIdx.x >> 5;
  int t0 = blockIdx.x * 32;   // seq tile
  int c0 = blockIdx.y * 32;   // channel tile (kv*128+d)
#pragma unroll
  for (int i = 0; i < 4; i++)
    tile[ty + i * 8][tx] = qkv[(size_t)(t0 + ty + i * 8) * QKVN + 5120 + c0 + tx];
  __syncthreads();
#pragma unroll
  for (int i = 0; i < 4; i++)
    vT[(size_t)(c0 + ty + i * 8) * TSEQ + t0 + tx] = tile[tx][ty + i * 8];
}

// ============ QKV GEMM: 256x192 tile, 3 phases x 16 MFMA, DEEP prefetch ============
// r9 lesson: gates waited on loads issued 1-2 phases earlier (~150-250ns) vs
// ~300-900ns memory latency -> exposed stall each K-tile. Fix: issue ALL 7
// loads of tile t+1 at P1(t) top (buffer dn free since P2(t-1)); gates now
// wait on loads issued 3+ phases back.
// Issue order (positions 1..7): B0,B1,B2,A0,A2,A1,A3.
//   P1 reads (worst wave): A-lo (A0|A2) + B n0,n1 (wc3 touches B2) = first 5.
//   P2 reads: A-hi (A1|A3) + B n2.
// Gates: P1-end  vmcnt(7) [t fully landed incl A1,A3; t+1's 7 fly] (last: 0)
//        P3-end  vmcnt(2) [first-5 of t+1 landed]                  (last: skip)
__global__ __launch_bounds__(512, 2) void k_gemmN192(const bf16_t* __restrict__ A,
                                                     const bf16_t* __restrict__ Bt,
                                                     bf16_t* __restrict__ Cout,
                                                     int M, int N, int K) {
  __shared__ bf16_t sA[2 * 256 * 64];    // 64 KB
  __shared__ bf16_t sB[2 * 192 * 64];    // 48 KB
  const int tid = threadIdx.x;
  const int lane = tid & 63, wave = tid >> 6;
  const int l15 = lane & 15, lhi = lane >> 4, l7 = l15 & 7;
  const int wr = wave >> 2, wc = wave & 3;
  const int wr128 = wr * 128, wc48 = wc * 48;
  const int bm = blockIdx.y * 256, bn = blockIdx.x * 192;
  const int nkt = K >> 6;

  const int r8 = tid >> 3;
  const int c16 = (tid & 7) ^ (r8 & 7);      // source pre-swizzle (T2)
  const bf16_t* Ag = A + (size_t)(bm + r8) * K + c16 * 8;
  const bf16_t* Bg = Bt + (size_t)(bn + r8) * K + c16 * 8;
  char* sAb = (char*)sA + wave * 1024;
  char* sBb = (char*)sB + wave * 1024;

#define STAGE_A(dst, bkk, r)                                                   \
  GLOAD_LDS16(Ag + (size_t)((r) * 64) * K + (bkk),                             \
              sAb + (dst) * 32768 + (r) * 8192)
#define STAGE_B(dst, bkk, q)                                                   \
  GLOAD_LDS16(Bg + (size_t)((q) * 64) * K + (bkk),                             \
              sBb + (dst) * 24576 + (q) * 8192)
// full-tile issue, order B0,B1,B2,A0,A2,A1,A3 (gate math depends on this)
#define STAGE_ALL(dst, bkk)                                                    \
  do {                                                                         \
    STAGE_B(dst, bkk, 0); STAGE_B(dst, bkk, 1); STAGE_B(dst, bkk, 2);          \
    STAGE_A(dst, bkk, 0); STAGE_A(dst, bkk, 2);                                \
    STAGE_A(dst, bkk, 1); STAGE_A(dst, bkk, 3);                                \
  } while (0)
#define RD_A(m, ks) (*(const bf16x8*)&sA[dofsA + ((wr128 + (m) * 16 + l15) << 6) + \
                                         ((((ks) * 4 + lhi) ^ l7) << 3)])
#define RD_B(n, ks) (*(const bf16x8*)&sB[dofsB + ((wc48 + (n) * 16 + l15) << 6) +  \
                                         ((((ks) * 4 + lhi) ^ l7) << 3)])

  f32x4 acc[8][3] = {};
  bf16x8 afL[4][2], afH[4][2], bf0[2], bf1[2], bf2[2];

  // prologue: stage tile 0; first-5 needed for P1(0)
  STAGE_ALL(0, 0);
  asm volatile("s_waitcnt vmcnt(2)" ::: "memory");
  __builtin_amdgcn_s_barrier();

  for (int t = 0; t < nkt; ++t) {
    const int d = t & 1, dn = d ^ 1;
    const int dofsA = d * 16384;
    const int dofsB = d * 12288;
    const int bk1 = (t + 1) << 6;
    const bool pf = (t + 1 < nkt);

    // ---------- P1: issue t+1 fully; read A-lo + B n0,n1; MFMA lo x {B0,B1} ----------
    if (pf) STAGE_ALL(dn, bk1);
#pragma unroll
    for (int m = 0; m < 4; m++)
#pragma unroll
      for (int ks = 0; ks < 2; ks++) afL[m][ks] = RD_A(m, ks);
#pragma unroll
    for (int ks = 0; ks < 2; ks++) { bf0[ks] = RD_B(0, ks); bf1[ks] = RD_B(1, ks); }
    __builtin_amdgcn_s_barrier();
    asm volatile("s_waitcnt lgkmcnt(0)" ::: "memory");
    __builtin_amdgcn_sched_barrier(0);
    __builtin_amdgcn_s_setprio(1);
#pragma unroll
    for (int m = 0; m < 4; m++)
#pragma unroll
      for (int ks = 0; ks < 2; ks++) {
        acc[m][0] = __builtin_amdgcn_mfma_f32_16x16x32_bf16(afL[m][ks], bf0[ks], acc[m][0], 0, 0, 0);
        acc[m][1] = __builtin_amdgcn_mfma_f32_16x16x32_bf16(afL[m][ks], bf1[ks], acc[m][1], 0, 0, 0);
      }
    __builtin_amdgcn_s_setprio(0);
    if (pf) asm volatile("s_waitcnt vmcnt(7)" ::: "memory");  // t fully landed (A1,A3)
    else    asm volatile("s_waitcnt vmcnt(0)" ::: "memory");
    __builtin_amdgcn_s_barrier();

    // ---------- P2: read A-hi + B n2; MFMA loxB2 + hixB0 ----------
#pragma unroll
    for (int m = 0; m < 4; m++)
#pragma unroll
      for (int ks = 0; ks < 2; ks++) afH[m][ks] = RD_A(4 + m, ks);
#pragma unroll
    for (int ks = 0; ks < 2; ks++) bf2[ks] = RD_B(2, ks);
    __builtin_amdgcn_s_barrier();
    asm volatile("s_waitcnt lgkmcnt(0)" ::: "memory");
    __builtin_amdgcn_sched_barrier(0);
    __builtin_amdgcn_s_setprio(1);
#pragma unroll
    for (int m = 0; m < 4; m++)
#pragma unroll
      for (int ks = 0; ks < 2; ks++) {
        acc[m][2] = __builtin_amdgcn_mfma_f32_16x16x32_bf16(afL[m][ks], bf2[ks], acc[m][2], 0, 0, 0);
        acc[4 + m][0] = __builtin_amdgcn_mfma_f32_16x16x32_bf16(afH[m][ks], bf0[ks], acc[4 + m][0], 0, 0, 0);
      }
    __builtin_amdgcn_s_setprio(0);
    __builtin_amdgcn_s_barrier();

    // ---------- P3: MFMA hi x {B1,B2} (regs only) ----------
    __builtin_amdgcn_s_setprio(1);
#pragma unroll
    for (int m = 0; m < 4; m++)
#pragma unroll
      for (int ks = 0; ks < 2; ks++) {
        acc[4 + m][1] = __builtin_amdgcn_mfma_f32_16x16x32_bf16(afH[m][ks], bf1[ks], acc[4 + m][1], 0, 0, 0);
        acc[4 + m][2] = __builtin_amdgcn_mfma_f32_16x16x32_bf16(afH[m][ks], bf2[ks], acc[4 + m][2], 0, 0, 0);
      }
    __builtin_amdgcn_s_setprio(0);
    if (pf) asm volatile("s_waitcnt vmcnt(2)" ::: "memory");  // first-5 of t+1 landed
    __builtin_amdgcn_s_barrier();
  }
#undef STAGE_A
#undef STAGE_B
#undef STAGE_ALL
#undef RD_A
#undef RD_B

  // epilogue (C/D layout: col=lane&15, row=(lane>>4)*4+reg)
#pragma unroll
  for (int m = 0; m < 8; m++)
#pragma unroll
    for (int n = 0; n < 3; n++)
#pragma unroll
      for (int b = 0; b < 4; b++) {
        int row = bm + wr128 + m * 16 + lhi * 4 + b;
        int col = bn + wc48 + n * 16 + l15;
        Cout[(size_t)row * N + col] = (bf16_t)acc[m][n][b];
      }
}

// ========= O-proj GEMM: 256x256 4-phase + split-K=2, DEEP prefetch =========
// blockIdx.z = K-slice; slice 0 -> C0 (d_out f32), slice 1 -> C1 (f32 partial).
// All 8 loads of t+1 issued at P1(t) top (order b0,b1,b2,b3,a0,a2,a1,a3).
//   P1 reads: A-lo (a0|a2) + b_wc  (within first 6).  P3 reads: A-hi (a1|a3).
// Gates: P2-end vmcnt(8) [t fully landed incl a1,a3 issued 5 phases back;
//        t+1's 8 fly] (last tile: vmcnt(0));  P4-end vmcnt(2) [first-6 of t+1].
__global__ __launch_bounds__(512, 2) void k_gemm256sk(const bf16_t* __restrict__ A,
                                                      const bf16_t* __restrict__ Bt,
                                                      float* __restrict__ C0,
                                                      float* __restrict__ C1,
                                                      int M, int N, int Kc, int lda) {
  __shared__ bf16_t sA[2 * 256 * 64];   // 64 KB
  __shared__ bf16_t sB[2 * 256 * 64];   // 64 KB
  const int tid = threadIdx.x;
  const int lane = tid & 63, wave = tid >> 6;
  const int l15 = lane & 15, lhi = lane >> 4, l7 = l15 & 7;
  const int wr = wave >> 2, wc = wave & 3;
  const int wr128 = wr * 128, wc64 = wc * 64;
  const int bm = blockIdx.y * 256, bn = blockIdx.x * 256;
  const int nkt = Kc >> 6;
  const int ksl = blockIdx.z;
  const bf16_t* Asl = A + (size_t)ksl * Kc;
  const bf16_t* Bsl = Bt + (size_t)ksl * Kc;
  float* Co = ksl ? C1 : C0;

  const int r8 = tid >> 3;
  const int c16 = (tid & 7) ^ (r8 & 7);
  const bf16_t* Ag = Asl + (size_t)(bm + r8) * lda + c16 * 8;
  const bf16_t* Bg = Bsl + (size_t)(bn + r8) * lda + c16 * 8;
  char* sAb = (char*)sA + wave * 1024;
  char* sBb = (char*)sB + wave * 1024;

#define STAGE(dst, bkk, q)                                                        \
  do {                                                                            \
    if ((q) < 4) {                                                                \
      GLOAD_LDS16(Bg + (size_t)((q) * 64) * lda + (bkk),                          \
                  sBb + (dst) * 32768 + (q) * 8192);                              \
    } else {                                                                      \
      const int ar2_ = ((((q) - 4) & 1) << 1) | ((((q) - 4) >> 1) & 1);           \
      GLOAD_LDS16(Ag + (size_t)(ar2_ * 64) * lda + (bkk),                         \
                  sAb + (dst) * 32768 + ar2_ * 8192);                             \
    }                                                                             \
  } while (0)
#define STAGE_ALL(dst, bkk)                                                       \
  do {                                                                            \
    STAGE(dst, bkk, 0); STAGE(dst, bkk, 1); STAGE(dst, bkk, 2); STAGE(dst, bkk, 3);\
    STAGE(dst, bkk, 4); STAGE(dst, bkk, 5); STAGE(dst, bkk, 6); STAGE(dst, bkk, 7);\
  } while (0)
#define RD_A(m, ks) (*(const bf16x8*)&sA[dofs + ((wr128 + (m) * 16 + l15) << 6) + \
                                         ((((ks) * 4 + lhi) ^ l7) << 3)])
#define RD_B(n, ks) (*(const bf16x8*)&sB[dofs + ((wc64 + (n) * 16 + l15) << 6) +  \
                                         ((((ks) * 4 + lhi) ^ l7) << 3)])

  f32x4 acc[8][4] = {};
  bf16x8 ar_[4][2], b01[2][2], b23[2][2];

  STAGE_ALL(0, 0);
  asm volatile("s_waitcnt vmcnt(2)" ::: "memory");
  __builtin_amdgcn_s_barrier();

  for (int t = 0; t < nkt; ++t) {
    const int d = t & 1, dn = d ^ 1;
    const int dofs = d * 16384;
    const int bk1 = (t + 1) << 6;
    const bool pf = (t + 1 < nkt);

    // ---------- Phase 1: issue t+1 fully; read A-lo + b01; MFMA Q00 ----------
    if (pf) STAGE_ALL(dn, bk1);
#pragma unroll
    for (int m = 0; m < 4; m++)
#pragma unroll
      for (int ks = 0; ks < 2; ks++) ar_[m][ks] = RD_A(m, ks);
#pragma unroll
    for (int n = 0; n < 2; n++)
#pragma unroll
      for (int ks = 0; ks < 2; ks++) b01[n][ks] = RD_B(n, ks);
    __builtin_amdgcn_s_barrier();
    asm volatile("s_waitcnt lgkmcnt(0)" ::: "memory");
    __builtin_amdgcn_sched_barrier(0);
    __builtin_amdgcn_s_setprio(1);
#pragma unroll
    for (int m = 0; m < 4; m++)
#pragma unroll
      for (int n = 0; n < 2; n++)
#pragma unroll
        for (int ks = 0; ks < 2; ks++)
          acc[m][n] = __builtin_amdgcn_mfma_f32_16x16x32_bf16(ar_[m][ks], b01[n][ks], acc[m][n], 0, 0, 0);
    __builtin_amdgcn_s_setprio(0);
    __builtin_amdgcn_s_barrier();

    // ---------- Phase 2: read b23; MFMA Q01; gate: drain t ----------
#pragma unroll
    for (int n = 0; n < 2; n++)
#pragma unroll
      for (int ks = 0; ks < 2; ks++) b23[n][ks] = RD_B(2 + n, ks);
    __builtin_amdgcn_s_barrier();
    asm volatile("s_waitcnt lgkmcnt(0)" ::: "memory");
    __builtin_amdgcn_sched_barrier(0);
    __builtin_amdgcn_s_setprio(1);
#pragma unroll
    for (int m = 0; m < 4; m++)
#pragma unroll
      for (int n = 0; n < 2; n++)
#pragma unroll
        for (int ks = 0; ks < 2; ks++)
          acc[m][2 + n] = __builtin_amdgcn_mfma_f32_16x16x32_bf16(ar_[m][ks], b23[n][ks], acc[m][2 + n], 0, 0, 0);
    __builtin_amdgcn_s_setprio(0);
    if (pf) asm volatile("s_waitcnt vmcnt(8)" ::: "memory");  // t fully landed (a1,a3)
    else    asm volatile("s_waitcnt vmcnt(0)" ::: "memory");
    __builtin_amdgcn_s_barrier();

    // ---------- Phase 3: read A-hi; MFMA Q11 ----------
#pragma unroll
    for (int m = 0; m < 4; m++)
#pragma unroll
      for (int ks = 0; ks < 2; ks++) ar_[m][ks] = RD_A(4 + m, ks);
    __builtin_amdgcn_s_barrier();
    asm volatile("s_waitcnt lgkmcnt(0)" ::: "memory");
    __builtin_amdgcn_sched_barrier(0);
    __builtin_amdgcn_s_setprio(1);
#pragma unroll
    for (int m = 0; m < 4; m++)
#pragma unroll
      for (int n = 0; n < 2; n++)
#pragma unroll
        for (int ks = 0; ks < 2; ks++)
          acc[4 + m][2 + n] = __builtin_amdgcn_mfma_f32_16x16x32_bf16(ar_[m][ks], b23[n][ks], acc[4 + m][2 + n], 0, 0, 0);
    __builtin_amdgcn_s_setprio(0);
    __builtin_amdgcn_s_barrier();

    // ---------- Phase 4: MFMA Q10 (regs only); gate: first-6 of t+1 ----------
    __builtin_amdgcn_s_setprio(1);
#pragma unroll
    for (int m = 0; m < 4; m++)
#pragma unroll
      for (int n = 0; n < 2; n++)
#pragma unroll
        for (int ks = 0; ks < 2; ks++)
          acc[4 + m][n] = __builtin_amdgcn_mfma_f32_16x16x32_bf16(ar_[m][ks], b01[n][ks], acc[4 + m][n], 0, 0, 0);
    __builtin_amdgcn_s_setprio(0);
    if (pf) asm volatile("s_waitcnt vmcnt(2)" ::: "memory");
    __builtin_amdgcn_s_barrier();
  }
#undef STAGE
#undef STAGE_ALL
#undef RD_A
#undef RD_B

#pragma unroll
  for (int m = 0; m < 8; m++)
#pragma unroll
    for (int n = 0; n < 4; n++)
#pragma unroll
      for (int b = 0; b < 4; b++) {
        int row = bm + wr128 + m * 16 + lhi * 4 + b;
        int col = bn + wc64 + n * 16 + l15;
        Co[(size_t)row * N + col] = acc[m][n][b];
      }
}

// ---------------- Flash attention v3 (causal, GQA) ----------------
__global__ __launch_bounds__(512, 2) void k_flash(const bf16_t* __restrict__ qkv,
                                                  const bf16_t* __restrict__ vT,
                                                  bf16_t* __restrict__ attn) {
  __shared__ bf16_t Kl[64][152];   // [s][d] pad 152
  __shared__ bf16_t Vl[128][88];   // [d][s] pad 88
  __shared__ bf16_t Pl[128][88];   // [t][s] pad 88
  const int h = blockIdx.x;
  const int by = blockIdx.y;
  const int qt = (by < 8) ? by : 23 - by;   // zig-zag: CU pair work sums const
  const int kvh = h >> 2;
  const int tid = threadIdx.x, lane = tid & 63, wave = tid >> 6;
  const int l15 = lane & 15, lhi = lane >> 4;
  const int qbase = qt * 128, wrow = wave * 16;

  bf16x8 qf[4];
#pragma unroll
  for (int ks = 0; ks < 4; ks++)
    qf[ks] = *(const bf16x8*)&qkv[(size_t)(qbase + wrow + l15) * QKVN +
                                  h * 128 + ks * 32 + lhi * 8];

  f32x4 o[8] = {};
  float m_i[4], l_i[4];
#pragma unroll
  for (int b = 0; b < 4; b++) { m_i[b] = -1e30f; l_i[b] = 0.f; }

  const int ks0 = tid >> 4, kd0 = (tid & 15) * 8;          // K rows 0..31 / 32..63
  const int vd0 = tid >> 3, vs0 = (tid & 7) * 8;           // V rows 0..63 / 64..127
  const bf16_t* Kg = qkv + 4096 + (size_t)kvh * 128;
  const bf16_t* Vg = vT + (size_t)(kvh * 128) * TSEQ;

  float4 rk0, rk1, rv0, rv1;   // buffer A
  float4 sk0, sk1, sv0, sv1;   // buffer B

#define LOADKV(a, b, c, d, ktl)                                                 \
  do {                                                                          \
    a = *(const float4*)&Kg[(size_t)((ktl) * 64 + ks0) * QKVN + kd0];           \
    b = *(const float4*)&Kg[(size_t)((ktl) * 64 + 32 + ks0) * QKVN + kd0];      \
    c = *(const float4*)&Vg[(size_t)vd0 * TSEQ + (ktl) * 64 + vs0];             \
    d = *(const float4*)&Vg[(size_t)(64 + vd0) * TSEQ + (ktl) * 64 + vs0];      \
  } while (0)

#define WRITEKV(a, b, c, d)                                                     \
  do {                                                                          \
    *(float4*)&Kl[ks0][kd0] = a;                                                \
    *(float4*)&Kl[32 + ks0][kd0] = b;                                           \
    *(float4*)&Vl[vd0][vs0] = c;                                                \
    *(float4*)&Vl[64 + vd0][vs0] = d;                                           \
  } while (0)

  const int ktmax = qt * 2 + 1;   // always odd -> even iteration count
  LOADKV(rk0, rk1, rv0, rv1, 0);

  for (int kt = 0; kt <= ktmax; kt += 2) {
#pragma unroll
    for (int sub = 0; sub < 2; ++sub) {
      const int ktc = kt + sub;
      __syncthreads();
      if (sub == 0) {
        WRITEKV(rk0, rk1, rv0, rv1);
        LOADKV(sk0, sk1, sv0, sv1, kt + 1);
      } else {
        WRITEKV(sk0, sk1, sv0, sv1);
        if (kt + 2 <= ktmax) LOADKV(rk0, rk1, rv0, rv1, kt + 2);
      }
      __syncthreads();

      f32x4 sa[4] = {};
#pragma unroll
      for (int ks = 0; ks < 4; ks++) {
        bf16x8 kb[4];
#pragma unroll
        for (int j = 0; j < 4; j++)
          kb[j] = *(const bf16x8*)&Kl[j * 16 + l15][ks * 32 + lhi * 8];
#pragma unroll
        for (int j = 0; j < 4; j++)
          sa[j] = __builtin_amdgcn_mfma_f32_16x16x32_bf16(qf[ks], kb[j], sa[j], 0, 0, 0);
      }
#pragma unroll
      for (int b = 0; b < 4; b++) {
        int trow = qbase + wrow + lhi * 4 + b;
        float mx = -1e30f;
#pragma unroll
        for (int j = 0; j < 4; j++) {
          int scol = ktc * 64 + j * 16 + l15;
          if (scol > trow) sa[j][b] = -1e30f;
          mx = fmaxf(mx, sa[j][b]);
        }
#pragma unroll
        for (int off = 1; off < 16; off <<= 1) mx = fmaxf(mx, __shfl_xor(mx, off));
        float mn = fmaxf(m_i[b], mx);
        float corr = __expf(m_i[b] - mn);
        float sum = 0.f;
#pragma unroll
        for (int j = 0; j < 4; j++) {
          float pv = __expf(sa[j][b] - mn);
          sa[j][b] = pv;
          sum += pv;
        }
#pragma unroll
        for (int off = 1; off < 16; off <<= 1) sum += __shfl_xor(sum, off);
        l_i[b] = l_i[b] * corr + sum;
        m_i[b] = mn;
#pragma unroll
        for (int j = 0; j < 8; j++) o[j][b] *= corr;
#pragma unroll
        for (int j = 0; j < 4; j++)
          Pl[wrow + lhi * 4 + b][j * 16 + l15] = (bf16_t)sa[j][b];
      }
#pragma unroll
      for (int ks = 0; ks < 2; ks++) {
        bf16x8 pa = *(const bf16x8*)&Pl[wrow + l15][ks * 32 + lhi * 8];
#pragma unroll
        for (int j = 0; j < 8; j++) {
          bf16x8 vb = *(const bf16x8*)&Vl[j * 16 + l15][ks * 32 + lhi * 8];
          o[j] = __builtin_amdgcn_mfma_f32_16x16x32_bf16(pa, vb, o[j], 0, 0, 0);
        }
      }
      __syncthreads();
    }
  }
#undef LOADKV
#undef WRITEKV

#pragma unroll
  for (int j = 0; j < 8; j++)
#pragma unroll
    for (int b = 0; b < 4; b++) {
      int trow = qbase + wrow + lhi * 4 + b;
      attn[(size_t)trow * (NH * HD) + h * 128 + j * 16 + l15] =
          (bf16_t)(o[j][b] / l_i[b]);
    }
}

// ---------------- launcher ----------------
extern "C" void kernel_launch(void* const* d_in, const int* in_sizes, int n_in,
                              void* d_out, int out_size, void* d_ws, size_t ws_size,
                              hipStream_t stream) {
  const int* positions = (const int*)d_in[0];
  const float* hs = (const float*)d_in[1];
  const float* wqkv = (const float*)d_in[2];
  const float* wo = (const float*)d_in[3];
  float* out = (float*)d_out;

  char* ws = (char*)d_ws;
  bf16_t* hsb   = (bf16_t*)(ws);                       // 16.78 MB (-> attn later)
  bf16_t* wqkvT = (bf16_t*)(ws + 16777216);            // 50.33 MB (-> part1 later)
  bf16_t* woT   = (bf16_t*)(ws + 67108864);            // 33.55 MB
  bf16_t* qkv   = (bf16_t*)(ws + 100663296);           // 25.17 MB
  bf16_t* vT    = (bf16_t*)(ws + 125829120);           //  4.19 MB
  bf16_t* attn  = hsb;                                 // reuse (hsb dead after GEMM1)
  float*  part1 = (float*)(ws + 16777216);             // reuse wqkvT (dead after QKV)

  // 1. convert hidden_states
  k_f32_to_bf16<<<(TSEQ * HID / 4 + 255) / 256, 256, 0, stream>>>(hs, hsb, TSEQ * HID);
  // 2. transpose-convert weights to [N][K]
  k_transpose_f32_bf16<<<dim3(QKVN / 32, HID / 32), 256, 0, stream>>>(wqkv, wqkvT, HID, QKVN);
  k_transpose_f32_bf16<<<dim3(HID / 32, HID / 32), 256, 0, stream>>>(wo, woT, NH * HD, HID);
  // 3. QKV projection (256x192 tiles, deep-prefetch 3-phase, 32x8 = 256 WGs)
  k_gemmN192<<<dim3(QKVN / 192, TSEQ / 256), 512, 0, stream>>>(hsb, wqkvT, qkv, TSEQ, QKVN, HID);
  // 4. RoPE in place (q scaled)
  k_rope<<<dim3(10, TSEQ), 256, 0, stream>>>(qkv, positions);
  // 5. transpose V -> vT [1024][T]
  k_transpose_v<<<dim3(TSEQ / 32, 1024 / 32), 256, 0, stream>>>(qkv, vT);
  // 6. flash attention -> attn bf16 [T][4096]
  k_flash<<<dim3(NH, 16), 512, 0, stream>>>(qkv, vT, attn);
  // 7. output projection: split-K=2, deep-prefetch 4-phase, 16x8x2 = 256 WGs
  k_gemm256sk<<<dim3(HID / 256, TSEQ / 256, 2), 512, 0, stream>>>(
      attn, woT, out, part1, TSEQ, HID, HID / 2, HID);
  // 8. out += part1
  k_addout<<<(TSEQ * HID / 4 + 255) / 256, 256, 0, stream>>>(out, part1, TSEQ * HID / 4);
}

// Round 11
// 341.154 us; speedup vs baseline: 1.1365x; 1.1365x over previous
//
#include <hip/hip_runtime.h>
#include <hip/hip_bf16.h>
#include <math.h>

// Problem constants
#define TSEQ   2048
#define HID    4096
#define NH     32
#define NKV    8
#define HD     128
#define QKVN   6144              // NH*HD + 2*NKV*HD
#define GSCALE 0.08838834764831845f   // HD^-0.5
#define LOG_THETA 13.122363377404328f // ln(500000)

typedef __bf16 bf16_t;
typedef __attribute__((ext_vector_type(8))) __bf16 bf16x8;
typedef __attribute__((ext_vector_type(4))) float f32x4;

// async global->LDS, 16B per lane; LDS dest is wave-uniform base + lane*16
#define GLOAD_LDS16(gp, lp)                                                    \
  __builtin_amdgcn_global_load_lds(                                            \
      (const __attribute__((address_space(1))) void*)(gp),                     \
      (__attribute__((address_space(3))) void*)(lp), 16, 0, 0)

// ---------------- f32 -> bf16 elementwise convert ----------------
__global__ __launch_bounds__(256) void k_f32_to_bf16(const float* __restrict__ in,
                                                     bf16_t* __restrict__ out, int n) {
  int i = (blockIdx.x * 256 + threadIdx.x) * 4;
  if (i >= n) return;
  float4 v = *(const float4*)(in + i);
  bf16_t o0 = (bf16_t)v.x, o1 = (bf16_t)v.y, o2 = (bf16_t)v.z, o3 = (bf16_t)v.w;
  typedef __attribute__((ext_vector_type(4))) __bf16 bf16x4;
  bf16x4 o = {o0, o1, o2, o3};
  *(bf16x4*)(out + i) = o;
}

// ---------------- out += part1 (f32, float4) ----------------
__global__ __launch_bounds__(256) void k_addout(float* __restrict__ out,
                                                const float* __restrict__ p1, int n4) {
  int i = blockIdx.x * 256 + threadIdx.x;
  if (i >= n4) return;
  float4 a = *(const float4*)(out + i * 4);
  float4 b = *(const float4*)(p1 + i * 4);
  a.x += b.x; a.y += b.y; a.z += b.z; a.w += b.w;
  *(float4*)(out + i * 4) = a;
}

// -------- f32 [R][C] -> bf16 [C][R], 64x64 tiles, both sides 16B-vectorized --------
// Old 32x32 kernel wrote scalar 2B bf16 (half-rate wave stores). Here: float4
// global reads -> LDS transpose (pad 66: 2-way write, ~2-way read aliasing) ->
// bf16x8 global writes. grid = (C/64, R/64), 256 threads.
__global__ __launch_bounds__(256) void k_transpose64(const float* __restrict__ in,
                                                     bf16_t* __restrict__ out,
                                                     int R, int C) {
  __shared__ bf16_t t64[64][66];
  const int tx = threadIdx.x & 15;   // 16 thr x float4 = 64 cols
  const int ty = threadIdx.x >> 4;   // 16 rows / iter
  const int r0 = blockIdx.y * 64, c0 = blockIdx.x * 64;
#pragma unroll
  for (int i = 0; i < 4; i++) {
    int r = ty + i * 16;
    float4 v = *(const float4*)&in[(size_t)(r0 + r) * C + c0 + tx * 4];
    t64[tx * 4 + 0][r] = (bf16_t)v.x;
    t64[tx * 4 + 1][r] = (bf16_t)v.y;
    t64[tx * 4 + 2][r] = (bf16_t)v.z;
    t64[tx * 4 + 3][r] = (bf16_t)v.w;
  }
  __syncthreads();
  const int ox = threadIdx.x & 7;    // 8 thr x bf16x8 = 64 elems per out-row
  const int oy = threadIdx.x >> 3;   // 32 out-rows / iter
#pragma unroll
  for (int i = 0; i < 2; i++) {
    int c = oy + i * 32;
    bf16x8 v = *(const bf16x8*)&t64[c][ox * 8];
    *(bf16x8*)&out[(size_t)(c0 + c) * R + r0 + ox * 8] = v;
  }
}

// ---------------- RoPE (interleaved) in-place on qkv; folds GSCALE into q ----------------
__global__ __launch_bounds__(256) void k_rope(bf16_t* __restrict__ qkv,
                                              const int* __restrict__ positions) {
  int idx = blockIdx.x * 256 + threadIdx.x;   // 0..2559 = 40 heads * 64 pairs
  int t = blockIdx.y;
  int i = idx & 63;          // pair index 0..63
  int hh = idx >> 6;         // 0..39 (0..31 = q heads, 32..39 = k heads)
  if (hh >= 40) return;
  int col = (hh < 32) ? (hh * 128 + 2 * i) : (4096 + (hh - 32) * 128 + 2 * i);
  size_t base = (size_t)t * QKVN + col;
  float x1 = (float)qkv[base];
  float x2 = (float)qkv[base + 1];
  float p = (float)positions[t];
  float inv = expf(-(float)i * (LOG_THETA / 64.0f));
  float ang = p * inv;
  float s, c;
  sincosf(ang, &s, &c);
  float o1 = x1 * c - x2 * s;
  float o2 = x2 * c + x1 * s;
  float sc = (hh < 32) ? GSCALE : 1.0f;
  qkv[base]     = (bf16_t)(o1 * sc);
  qkv[base + 1] = (bf16_t)(o2 * sc);
}

// ---------------- transpose V: qkv[:, 5120+c] (T x 1024) -> vT [1024][T] ----------------
__global__ __launch_bounds__(256) void k_transpose_v(const bf16_t* __restrict__ qkv,
                                                     bf16_t* __restrict__ vT) {
  __shared__ bf16_t tile[32][33];
  int tx = threadIdx.x & 31, ty = threadIdx.x >> 5;
  int t0 = blockIdx.x * 32;   // seq tile
  int c0 = blockIdx.y * 32;   // channel tile (kv*128+d)
#pragma unroll
  for (int i = 0; i < 4; i++)
    tile[ty + i * 8][tx] = qkv[(size_t)(t0 + ty + i * 8) * QKVN + 5120 + c0 + tx];
  __syncthreads();
#pragma unroll
  for (int i = 0; i < 4; i++)
    vT[(size_t)(c0 + ty + i * 8) * TSEQ + t0 + tx] = tile[tx][ty + i * 8];
}

// ============ QKV GEMM: 256x192 tile, 3 phases x 16 MFMA (r9-benched, 123us) ============
// Staged issue (NOT burst — r10's all-at-P1-top burst regressed 123->153us):
// P1 stages A0-3(t+1), P2 stages B0,B1(t+1), P3 stages B2(t+1).
// Gates: P1-end vmcnt(4) [B2(t) landed for P2] (last tile: 0);
//        P3-end vmcnt(1) [A0-3,B0,B1(t+1) landed for next P1].
__global__ __launch_bounds__(512, 2) void k_gemmN192(const bf16_t* __restrict__ A,
                                                     const bf16_t* __restrict__ Bt,
                                                     bf16_t* __restrict__ Cout,
                                                     int M, int N, int K) {
  __shared__ bf16_t sA[2 * 256 * 64];    // 64 KB
  __shared__ bf16_t sB[2 * 192 * 64];    // 48 KB
  const int tid = threadIdx.x;
  const int lane = tid & 63, wave = tid >> 6;
  const int l15 = lane & 15, lhi = lane >> 4, l7 = l15 & 7;
  const int wr = wave >> 2, wc = wave & 3;
  const int wr128 = wr * 128, wc48 = wc * 48;
  const int bm = blockIdx.y * 256, bn = blockIdx.x * 192;
  const int nkt = K >> 6;

  const int r8 = tid >> 3;
  const int c16 = (tid & 7) ^ (r8 & 7);      // source pre-swizzle (T2)
  const bf16_t* Ag = A + (size_t)(bm + r8) * K + c16 * 8;
  const bf16_t* Bg = Bt + (size_t)(bn + r8) * K + c16 * 8;
  char* sAb = (char*)sA + wave * 1024;
  char* sBb = (char*)sB + wave * 1024;

#define STAGE_A(dst, bkk, r)                                                   \
  GLOAD_LDS16(Ag + (size_t)((r) * 64) * K + (bkk),                             \
              sAb + (dst) * 32768 + (r) * 8192)
#define STAGE_B(dst, bkk, q)                                                   \
  GLOAD_LDS16(Bg + (size_t)((q) * 64) * K + (bkk),                             \
              sBb + (dst) * 24576 + (q) * 8192)
#define RD_A(m, ks) (*(const bf16x8*)&sA[dofsA + ((wr128 + (m) * 16 + l15) << 6) + \
                                         ((((ks) * 4 + lhi) ^ l7) << 3)])
#define RD_B(n, ks) (*(const bf16x8*)&sB[dofsB + ((wc48 + (n) * 16 + l15) << 6) +  \
                                         ((((ks) * 4 + lhi) ^ l7) << 3)])

  f32x4 acc[8][3] = {};
  bf16x8 afL[4][2], afH[4][2], bf0[2], bf1[2], bf2[2];

  // prologue: stage tile 0 (order A0-3, B0-2); wait all but B2
  STAGE_A(0, 0, 0); STAGE_A(0, 0, 1); STAGE_A(0, 0, 2); STAGE_A(0, 0, 3);
  STAGE_B(0, 0, 0); STAGE_B(0, 0, 1); STAGE_B(0, 0, 2);
  asm volatile("s_waitcnt vmcnt(1)" ::: "memory");
  __builtin_amdgcn_s_barrier();

  for (int t = 0; t < nkt; ++t) {
    const int d = t & 1, dn = d ^ 1;
    const int dofsA = d * 16384;
    const int dofsB = d * 12288;
    const int bk1 = (t + 1) << 6;
    const bool pf = (t + 1 < nkt);

    // ---------- P1: read A-lo + B0,B1; stage A(t+1); MFMA lo x {B0,B1} ----------
#pragma unroll
    for (int m = 0; m < 4; m++)
#pragma unroll
      for (int ks = 0; ks < 2; ks++) afL[m][ks] = RD_A(m, ks);
#pragma unroll
    for (int ks = 0; ks < 2; ks++) { bf0[ks] = RD_B(0, ks); bf1[ks] = RD_B(1, ks); }
    if (pf) { STAGE_A(dn, bk1, 0); STAGE_A(dn, bk1, 1); STAGE_A(dn, bk1, 2); STAGE_A(dn, bk1, 3); }
    __builtin_amdgcn_s_barrier();
    asm volatile("s_waitcnt lgkmcnt(0)" ::: "memory");
    __builtin_amdgcn_sched_barrier(0);
    __builtin_amdgcn_s_setprio(1);
#pragma unroll
    for (int m = 0; m < 4; m++)
#pragma unroll
      for (int ks = 0; ks < 2; ks++) {
        acc[m][0] = __builtin_amdgcn_mfma_f32_16x16x32_bf16(afL[m][ks], bf0[ks], acc[m][0], 0, 0, 0);
        acc[m][1] = __builtin_amdgcn_mfma_f32_16x16x32_bf16(afL[m][ks], bf1[ks], acc[m][1], 0, 0, 0);
      }
    __builtin_amdgcn_s_setprio(0);
    if (pf) asm volatile("s_waitcnt vmcnt(4)" ::: "memory");  // B2(t) landed
    else    asm volatile("s_waitcnt vmcnt(0)" ::: "memory");
    __builtin_amdgcn_s_barrier();

    // ---------- P2: read A-hi + B2; stage B0,B1(t+1); MFMA loxB2 + hixB0 ----------
#pragma unroll
    for (int m = 0; m < 4; m++)
#pragma unroll
      for (int ks = 0; ks < 2; ks++) afH[m][ks] = RD_A(4 + m, ks);
#pragma unroll
    for (int ks = 0; ks < 2; ks++) bf2[ks] = RD_B(2, ks);
    if (pf) { STAGE_B(dn, bk1, 0); STAGE_B(dn, bk1, 1); }
    __builtin_amdgcn_s_barrier();
    asm volatile("s_waitcnt lgkmcnt(0)" ::: "memory");
    __builtin_amdgcn_sched_barrier(0);
    __builtin_amdgcn_s_setprio(1);
#pragma unroll
    for (int m = 0; m < 4; m++)
#pragma unroll
      for (int ks = 0; ks < 2; ks++) {
        acc[m][2] = __builtin_amdgcn_mfma_f32_16x16x32_bf16(afL[m][ks], bf2[ks], acc[m][2], 0, 0, 0);
        acc[4 + m][0] = __builtin_amdgcn_mfma_f32_16x16x32_bf16(afH[m][ks], bf0[ks], acc[4 + m][0], 0, 0, 0);
      }
    __builtin_amdgcn_s_setprio(0);
    __builtin_amdgcn_s_barrier();

    // ---------- P3: stage B2(t+1); MFMA hi x {B1,B2} ----------
    if (pf) STAGE_B(dn, bk1, 2);
    __builtin_amdgcn_s_setprio(1);
#pragma unroll
    for (int m = 0; m < 4; m++)
#pragma unroll
      for (int ks = 0; ks < 2; ks++) {
        acc[4 + m][1] = __builtin_amdgcn_mfma_f32_16x16x32_bf16(afH[m][ks], bf1[ks], acc[4 + m][1], 0, 0, 0);
        acc[4 + m][2] = __builtin_amdgcn_mfma_f32_16x16x32_bf16(afH[m][ks], bf2[ks], acc[4 + m][2], 0, 0, 0);
      }
    __builtin_amdgcn_s_setprio(0);
    if (pf) asm volatile("s_waitcnt vmcnt(1)" ::: "memory");  // A0-3,B0,B1(t+1) landed
    __builtin_amdgcn_s_barrier();
  }
#undef STAGE_A
#undef STAGE_B
#undef RD_A
#undef RD_B

  // epilogue (C/D layout: col=lane&15, row=(lane>>4)*4+reg)
#pragma unroll
  for (int m = 0; m < 8; m++)
#pragma unroll
    for (int n = 0; n < 3; n++)
#pragma unroll
      for (int b = 0; b < 4; b++) {
        int row = bm + wr128 + m * 16 + lhi * 4 + b;
        int col = bn + wc48 + n * 16 + l15;
        Cout[(size_t)row * N + col] = (bf16_t)acc[m][n][b];
      }
}

// ========= O-proj GEMM: 256x256 8-phase + split-K=2 (r9-benched) =========
// blockIdx.z = K-slice; slice 0 -> C0 (d_out f32), slice 1 -> C1 (f32 partial).
// Staged issue 2/phase (proven r4 ladder): vmcnt(4)@P2-end, vmcnt(2)@P4-end.
__global__ __launch_bounds__(512, 2) void k_gemm256sk(const bf16_t* __restrict__ A,
                                                      const bf16_t* __restrict__ Bt,
                                                      float* __restrict__ C0,
                                                      float* __restrict__ C1,
                                                      int M, int N, int Kc, int lda) {
  __shared__ bf16_t sA[2 * 256 * 64];   // 64 KB
  __shared__ bf16_t sB[2 * 256 * 64];   // 64 KB
  const int tid = threadIdx.x;
  const int lane = tid & 63, wave = tid >> 6;
  const int l15 = lane & 15, lhi = lane >> 4, l7 = l15 & 7;
  const int wr = wave >> 2, wc = wave & 3;
  const int wr128 = wr * 128, wc64 = wc * 64;
  const int bm = blockIdx.y * 256, bn = blockIdx.x * 256;
  const int nkt = Kc >> 6;
  const int ksl = blockIdx.z;
  const bf16_t* Asl = A + (size_t)ksl * Kc;
  const bf16_t* Bsl = Bt + (size_t)ksl * Kc;
  float* Co = ksl ? C1 : C0;

  const int r8 = tid >> 3;
  const int c16 = (tid & 7) ^ (r8 & 7);
  const bf16_t* Ag = Asl + (size_t)(bm + r8) * lda + c16 * 8;
  const bf16_t* Bg = Bsl + (size_t)(bn + r8) * lda + c16 * 8;
  char* sAb = (char*)sA + wave * 1024;
  char* sBb = (char*)sB + wave * 1024;

#define STAGE(dst, bkk, q)                                                        \
  do {                                                                            \
    if ((q) < 4) {                                                                \
      GLOAD_LDS16(Bg + (size_t)((q) * 64) * lda + (bkk),                          \
                  sBb + (dst) * 32768 + (q) * 8192);                              \
    } else {                                                                      \
      const int ar2_ = ((((q) - 4) & 1) << 1) | ((((q) - 4) >> 1) & 1);           \
      GLOAD_LDS16(Ag + (size_t)(ar2_ * 64) * lda + (bkk),                         \
                  sAb + (dst) * 32768 + ar2_ * 8192);                             \
    }                                                                             \
  } while (0)
#define RD_A(m, ks) (*(const bf16x8*)&sA[dofs + ((wr128 + (m) * 16 + l15) << 6) + \
                                         ((((ks) * 4 + lhi) ^ l7) << 3)])
#define RD_B(n, ks) (*(const bf16x8*)&sB[dofs + ((wc64 + (n) * 16 + l15) << 6) +  \
                                         ((((ks) * 4 + lhi) ^ l7) << 3)])

  f32x4 acc[8][4] = {};
  bf16x8 ar_[4][2], b01[2][2], b23[2][2];

  STAGE(0, 0, 0); STAGE(0, 0, 1); STAGE(0, 0, 2); STAGE(0, 0, 3);
  STAGE(0, 0, 4); STAGE(0, 0, 5); STAGE(0, 0, 6); STAGE(0, 0, 7);
  asm volatile("s_waitcnt vmcnt(2)" ::: "memory");
  __builtin_amdgcn_s_barrier();

  for (int t = 0; t < nkt; ++t) {
    const int d = t & 1, dn = d ^ 1;
    const int dofs = d * 16384;
    const int bk1 = (t + 1) << 6;
    const bool pf = (t + 1 < nkt);

    // ---------- Phase 1 ----------
#pragma unroll
    for (int m = 0; m < 4; m++)
#pragma unroll
      for (int ks = 0; ks < 2; ks++) ar_[m][ks] = RD_A(m, ks);
#pragma unroll
    for (int n = 0; n < 2; n++)
#pragma unroll
      for (int ks = 0; ks < 2; ks++) b01[n][ks] = RD_B(n, ks);
    if (pf) { STAGE(dn, bk1, 0); STAGE(dn, bk1, 1); }
    __builtin_amdgcn_s_barrier();
    asm volatile("s_waitcnt lgkmcnt(0)" ::: "memory");
    __builtin_amdgcn_sched_barrier(0);
    __builtin_amdgcn_s_setprio(1);
#pragma unroll
    for (int m = 0; m < 4; m++)
#pragma unroll
      for (int n = 0; n < 2; n++)
#pragma unroll
        for (int ks = 0; ks < 2; ks++)
          acc[m][n] = __builtin_amdgcn_mfma_f32_16x16x32_bf16(ar_[m][ks], b01[n][ks], acc[m][n], 0, 0, 0);
    __builtin_amdgcn_s_setprio(0);
    __builtin_amdgcn_s_barrier();

    // ---------- Phase 2 ----------
#pragma unroll
    for (int n = 0; n < 2; n++)
#pragma unroll
      for (int ks = 0; ks < 2; ks++) b23[n][ks] = RD_B(2 + n, ks);
    if (pf) { STAGE(dn, bk1, 2); STAGE(dn, bk1, 3); }
    __builtin_amdgcn_s_barrier();
    asm volatile("s_waitcnt lgkmcnt(0)" ::: "memory");
    __builtin_amdgcn_sched_barrier(0);
    __builtin_amdgcn_s_setprio(1);
#pragma unroll
    for (int m = 0; m < 4; m++)
#pragma unroll
      for (int n = 0; n < 2; n++)
#pragma unroll
        for (int ks = 0; ks < 2; ks++)
          acc[m][2 + n] = __builtin_amdgcn_mfma_f32_16x16x32_bf16(ar_[m][ks], b23[n][ks], acc[m][2 + n], 0, 0, 0);
    __builtin_amdgcn_s_setprio(0);
    asm volatile("s_waitcnt vmcnt(4)" ::: "memory");
    __builtin_amdgcn_s_barrier();

    // ---------- Phase 3 ----------
#pragma unroll
    for (int m = 0; m < 4; m++)
#pragma unroll
      for (int ks = 0; ks < 2; ks++) ar_[m][ks] = RD_A(4 + m, ks);
    if (pf) { STAGE(dn, bk1, 4); STAGE(dn, bk1, 5); }
    __builtin_amdgcn_s_barrier();
    asm volatile("s_waitcnt lgkmcnt(0)" ::: "memory");
    __builtin_amdgcn_sched_barrier(0);
    __builtin_amdgcn_s_setprio(1);
#pragma unroll
    for (int m = 0; m < 4; m++)
#pragma unroll
      for (int n = 0; n < 2; n++)
#pragma unroll
        for (int ks = 0; ks < 2; ks++)
          acc[4 + m][2 + n] = __builtin_amdgcn_mfma_f32_16x16x32_bf16(ar_[m][ks], b23[n][ks], acc[4 + m][2 + n], 0, 0, 0);
    __builtin_amdgcn_s_setprio(0);
    __builtin_amdgcn_s_barrier();

    // ---------- Phase 4 ----------
    if (pf) { STAGE(dn, bk1, 6); STAGE(dn, bk1, 7); }
    __builtin_amdgcn_s_barrier();
    __builtin_amdgcn_s_setprio(1);
#pragma unroll
    for (int m = 0; m < 4; m++)
#pragma unroll
      for (int n = 0; n < 2; n++)
#pragma unroll
        for (int ks = 0; ks < 2; ks++)
          acc[4 + m][n] = __builtin_amdgcn_mfma_f32_16x16x32_bf16(ar_[m][ks], b01[n][ks], acc[4 + m][n], 0, 0, 0);
    __builtin_amdgcn_s_setprio(0);
    asm volatile("s_waitcnt vmcnt(2)" ::: "memory");
    __builtin_amdgcn_s_barrier();
  }
#undef STAGE
#undef RD_A
#undef RD_B

#pragma unroll
  for (int m = 0; m < 8; m++)
#pragma unroll
    for (int n = 0; n < 4; n++)
#pragma unroll
      for (int b = 0; b < 4; b++) {
        int row = bm + wr128 + m * 16 + lhi * 4 + b;
        int col = bn + wc64 + n * 16 + l15;
        Co[(size_t)row * N + col] = acc[m][n][b];
      }
}

// ---------------- Flash attention v3 + T5 setprio (causal, GQA) ----------------
__global__ __launch_bounds__(512, 2) void k_flash(const bf16_t* __restrict__ qkv,
                                                  const bf16_t* __restrict__ vT,
                                                  bf16_t* __restrict__ attn) {
  __shared__ bf16_t Kl[64][152];   // [s][d] pad 152
  __shared__ bf16_t Vl[128][88];   // [d][s] pad 88
  __shared__ bf16_t Pl[128][88];   // [t][s] pad 88
  const int h = blockIdx.x;
  const int by = blockIdx.y;
  const int qt = (by < 8) ? by : 23 - by;   // zig-zag: CU pair work sums const
  const int kvh = h >> 2;
  const int tid = threadIdx.x, lane = tid & 63, wave = tid >> 6;
  const int l15 = lane & 15, lhi = lane >> 4;
  const int qbase = qt * 128, wrow = wave * 16;

  bf16x8 qf[4];
#pragma unroll
  for (int ks = 0; ks < 4; ks++)
    qf[ks] = *(const bf16x8*)&qkv[(size_t)(qbase + wrow + l15) * QKVN +
                                  h * 128 + ks * 32 + lhi * 8];

  f32x4 o[8] = {};
  float m_i[4], l_i[4];
#pragma unroll
  for (int b = 0; b < 4; b++) { m_i[b] = -1e30f; l_i[b] = 0.f; }

  const int ks0 = tid >> 4, kd0 = (tid & 15) * 8;          // K rows 0..31 / 32..63
  const int vd0 = tid >> 3, vs0 = (tid & 7) * 8;           // V rows 0..63 / 64..127
  const bf16_t* Kg = qkv + 4096 + (size_t)kvh * 128;
  const bf16_t* Vg = vT + (size_t)(kvh * 128) * TSEQ;

  float4 rk0, rk1, rv0, rv1;   // buffer A
  float4 sk0, sk1, sv0, sv1;   // buffer B

#define LOADKV(a, b, c, d, ktl)                                                 \
  do {                                                                          \
    a = *(const float4*)&Kg[(size_t)((ktl) * 64 + ks0) * QKVN + kd0];           \
    b = *(const float4*)&Kg[(size_t)((ktl) * 64 + 32 + ks0) * QKVN + kd0];      \
    c = *(const float4*)&Vg[(size_t)vd0 * TSEQ + (ktl) * 64 + vs0];             \
    d = *(const float4*)&Vg[(size_t)(64 + vd0) * TSEQ + (ktl) * 64 + vs0];      \
  } while (0)

#define WRITEKV(a, b, c, d)                                                     \
  do {                                                                          \
    *(float4*)&Kl[ks0][kd0] = a;                                                \
    *(float4*)&Kl[32 + ks0][kd0] = b;                                           \
    *(float4*)&Vl[vd0][vs0] = c;                                                \
    *(float4*)&Vl[64 + vd0][vs0] = d;                                           \
  } while (0)

  const int ktmax = qt * 2 + 1;   // always odd -> even iteration count
  LOADKV(rk0, rk1, rv0, rv1, 0);

  for (int kt = 0; kt <= ktmax; kt += 2) {
#pragma unroll
    for (int sub = 0; sub < 2; ++sub) {
      const int ktc = kt + sub;
      __syncthreads();
      if (sub == 0) {
        WRITEKV(rk0, rk1, rv0, rv1);
        LOADKV(sk0, sk1, sv0, sv1, kt + 1);
      } else {
        WRITEKV(sk0, sk1, sv0, sv1);
        if (kt + 2 <= ktmax) LOADKV(rk0, rk1, rv0, rv1, kt + 2);
      }
      __syncthreads();

      f32x4 sa[4] = {};
      __builtin_amdgcn_s_setprio(1);   // T5: favor this wave's MFMA cluster
#pragma unroll
      for (int ks = 0; ks < 4; ks++) {
        bf16x8 kb[4];
#pragma unroll
        for (int j = 0; j < 4; j++)
          kb[j] = *(const bf16x8*)&Kl[j * 16 + l15][ks * 32 + lhi * 8];
#pragma unroll
        for (int j = 0; j < 4; j++)
          sa[j] = __builtin_amdgcn_mfma_f32_16x16x32_bf16(qf[ks], kb[j], sa[j], 0, 0, 0);
      }
      __builtin_amdgcn_s_setprio(0);
#pragma unroll
      for (int b = 0; b < 4; b++) {
        int trow = qbase + wrow + lhi * 4 + b;
        float mx = -1e30f;
#pragma unroll
        for (int j = 0; j < 4; j++) {
          int scol = ktc * 64 + j * 16 + l15;
          if (scol > trow) sa[j][b] = -1e30f;
          mx = fmaxf(mx, sa[j][b]);
        }
#pragma unroll
        for (int off = 1; off < 16; off <<= 1) mx = fmaxf(mx, __shfl_xor(mx, off));
        float mn = fmaxf(m_i[b], mx);
        float corr = __expf(m_i[b] - mn);
        float sum = 0.f;
#pragma unroll
        for (int j = 0; j < 4; j++) {
          float pv = __expf(sa[j][b] - mn);
          sa[j][b] = pv;
          sum += pv;
        }
#pragma unroll
        for (int off = 1; off < 16; off <<= 1) sum += __shfl_xor(sum, off);
        l_i[b] = l_i[b] * corr + sum;
        m_i[b] = mn;
#pragma unroll
        for (int j = 0; j < 8; j++) o[j][b] *= corr;
#pragma unroll
        for (int j = 0; j < 4; j++)
          Pl[wrow + lhi * 4 + b][j * 16 + l15] = (bf16_t)sa[j][b];
      }
      __builtin_amdgcn_s_setprio(1);   // T5: PV cluster
#pragma unroll
      for (int ks = 0; ks < 2; ks++) {
        bf16x8 pa = *(const bf16x8*)&Pl[wrow + l15][ks * 32 + lhi * 8];
#pragma unroll
        for (int j = 0; j < 8; j++) {
          bf16x8 vb = *(const bf16x8*)&Vl[j * 16 + l15][ks * 32 + lhi * 8];
          o[j] = __builtin_amdgcn_mfma_f32_16x16x32_bf16(pa, vb, o[j], 0, 0, 0);
        }
      }
      __builtin_amdgcn_s_setprio(0);
      __syncthreads();
    }
  }
#undef LOADKV
#undef WRITEKV

#pragma unroll
  for (int j = 0; j < 8; j++)
#pragma unroll
    for (int b = 0; b < 4; b++) {
      int trow = qbase + wrow + lhi * 4 + b;
      attn[(size_t)trow * (NH * HD) + h * 128 + j * 16 + l15] =
          (bf16_t)(o[j][b] / l_i[b]);
    }
}

// ---------------- launcher ----------------
extern "C" void kernel_launch(void* const* d_in, const int* in_sizes, int n_in,
                              void* d_out, int out_size, void* d_ws, size_t ws_size,
                              hipStream_t stream) {
  const int* positions = (const int*)d_in[0];
  const float* hs = (const float*)d_in[1];
  const float* wqkv = (const float*)d_in[2];
  const float* wo = (const float*)d_in[3];
  float* out = (float*)d_out;

  char* ws = (char*)d_ws;
  bf16_t* hsb   = (bf16_t*)(ws);                       // 16.78 MB (-> attn later)
  bf16_t* wqkvT = (bf16_t*)(ws + 16777216);            // 50.33 MB (-> part1 later)
  bf16_t* woT   = (bf16_t*)(ws + 67108864);            // 33.55 MB
  bf16_t* qkv   = (bf16_t*)(ws + 100663296);           // 25.17 MB
  bf16_t* vT    = (bf16_t*)(ws + 125829120);           //  4.19 MB
  bf16_t* attn  = hsb;                                 // reuse (hsb dead after GEMM1)
  float*  part1 = (float*)(ws + 16777216);             // reuse wqkvT (dead after QKV)

  // 1. convert hidden_states
  k_f32_to_bf16<<<(TSEQ * HID / 4 + 255) / 256, 256, 0, stream>>>(hs, hsb, TSEQ * HID);
  // 2. transpose-convert weights to [N][K] (64x64 vectorized tiles)
  k_transpose64<<<dim3(QKVN / 64, HID / 64), 256, 0, stream>>>(wqkv, wqkvT, HID, QKVN);
  k_transpose64<<<dim3(HID / 64, (NH * HD) / 64), 256, 0, stream>>>(wo, woT, NH * HD, HID);
  // 3. QKV projection (256x192 tiles, staged 3-phase, 32x8 = 256 WGs)
  k_gemmN192<<<dim3(QKVN / 192, TSEQ / 256), 512, 0, stream>>>(hsb, wqkvT, qkv, TSEQ, QKVN, HID);
  // 4. RoPE in place (q scaled)
  k_rope<<<dim3(10, TSEQ), 256, 0, stream>>>(qkv, positions);
  // 5. transpose V -> vT [1024][T]
  k_transpose_v<<<dim3(TSEQ / 32, 1024 / 32), 256, 0, stream>>>(qkv, vT);
  // 6. flash attention -> attn bf16 [T][4096]
  k_flash<<<dim3(NH, 16), 512, 0, stream>>>(qkv, vT, attn);
  // 7. output projection: split-K=2, 8-phase 256^2, 16x8x2 = 256 WGs
  k_gemm256sk<<<dim3(HID / 256, TSEQ / 256, 2), 512, 0, stream>>>(
      attn, woT, out, part1, TSEQ, HID, HID / 2, HID);
  // 8. out += part1
  k_addout<<<(TSEQ * HID / 4 + 255) / 256, 256, 0, stream>>>(out, part1, TSEQ * HID / 4);
}

// Round 12
// 329.282 us; speedup vs baseline: 1.1775x; 1.0361x over previous
//
#include <hip/hip_runtime.h>
#include <hip/hip_bf16.h>
#include <math.h>

// Problem constants
#define TSEQ   2048
#define HID    4096
#define NH     32
#define NKV    8
#define HD     128
#define QKVN   6144              // NH*HD + 2*NKV*HD
#define GSCALE 0.08838834764831845f   // HD^-0.5
#define LOG_THETA 13.122363377404328f // ln(500000)

typedef __bf16 bf16_t;
typedef __attribute__((ext_vector_type(8))) __bf16 bf16x8;
typedef __attribute__((ext_vector_type(4))) float f32x4;

// async global->LDS, 16B per lane; LDS dest is wave-uniform base + lane*16
#define GLOAD_LDS16(gp, lp)                                                    \
  __builtin_amdgcn_global_load_lds(                                            \
      (const __attribute__((address_space(1))) void*)(gp),                     \
      (__attribute__((address_space(3))) void*)(lp), 16, 0, 0)

// ---------------- f32 -> bf16 elementwise convert ----------------
__global__ __launch_bounds__(256) void k_f32_to_bf16(const float* __restrict__ in,
                                                     bf16_t* __restrict__ out, int n) {
  int i = (blockIdx.x * 256 + threadIdx.x) * 4;
  if (i >= n) return;
  float4 v = *(const float4*)(in + i);
  bf16_t o0 = (bf16_t)v.x, o1 = (bf16_t)v.y, o2 = (bf16_t)v.z, o3 = (bf16_t)v.w;
  typedef __attribute__((ext_vector_type(4))) __bf16 bf16x4;
  bf16x4 o = {o0, o1, o2, o3};
  *(bf16x4*)(out + i) = o;
}

// -------- f32 [R][C] -> bf16 [C][R], 64x64 tiles, both sides 16B-vectorized --------
__global__ __launch_bounds__(256) void k_transpose64(const float* __restrict__ in,
                                                     bf16_t* __restrict__ out,
                                                     int R, int C) {
  __shared__ bf16_t t64[64][66];
  const int tx = threadIdx.x & 15;   // 16 thr x float4 = 64 cols
  const int ty = threadIdx.x >> 4;   // 16 rows / iter
  const int r0 = blockIdx.y * 64, c0 = blockIdx.x * 64;
#pragma unroll
  for (int i = 0; i < 4; i++) {
    int r = ty + i * 16;
    float4 v = *(const float4*)&in[(size_t)(r0 + r) * C + c0 + tx * 4];
    t64[tx * 4 + 0][r] = (bf16_t)v.x;
    t64[tx * 4 + 1][r] = (bf16_t)v.y;
    t64[tx * 4 + 2][r] = (bf16_t)v.z;
    t64[tx * 4 + 3][r] = (bf16_t)v.w;
  }
  __syncthreads();
  const int ox = threadIdx.x & 7;    // 8 thr x bf16x8 = 64 elems per out-row
  const int oy = threadIdx.x >> 3;   // 32 out-rows / iter
#pragma unroll
  for (int i = 0; i < 2; i++) {
    int c = oy + i * 32;
    bf16x8 v = *(const bf16x8*)&t64[c][ox * 8];
    *(bf16x8*)&out[(size_t)(c0 + c) * R + r0 + ox * 8] = v;
  }
}

// ---------------- RoPE (interleaved) in-place on qkv; folds GSCALE into q ----------------
__global__ __launch_bounds__(256) void k_rope(bf16_t* __restrict__ qkv,
                                              const int* __restrict__ positions) {
  int idx = blockIdx.x * 256 + threadIdx.x;   // 0..2559 = 40 heads * 64 pairs
  int t = blockIdx.y;
  int i = idx & 63;          // pair index 0..63
  int hh = idx >> 6;         // 0..39 (0..31 = q heads, 32..39 = k heads)
  if (hh >= 40) return;
  int col = (hh < 32) ? (hh * 128 + 2 * i) : (4096 + (hh - 32) * 128 + 2 * i);
  size_t base = (size_t)t * QKVN + col;
  float x1 = (float)qkv[base];
  float x2 = (float)qkv[base + 1];
  float p = (float)positions[t];
  float inv = expf(-(float)i * (LOG_THETA / 64.0f));
  float ang = p * inv;
  float s, c;
  sincosf(ang, &s, &c);
  float o1 = x1 * c - x2 * s;
  float o2 = x2 * c + x1 * s;
  float sc = (hh < 32) ? GSCALE : 1.0f;
  qkv[base]     = (bf16_t)(o1 * sc);
  qkv[base + 1] = (bf16_t)(o2 * sc);
}

// ---------------- transpose V: qkv[:, 5120+c] (T x 1024) -> vT [1024][T] ----------------
__global__ __launch_bounds__(256) void k_transpose_v(const bf16_t* __restrict__ qkv,
                                                     bf16_t* __restrict__ vT) {
  __shared__ bf16_t tile[32][33];
  int tx = threadIdx.x & 31, ty = threadIdx.x >> 5;
  int t0 = blockIdx.x * 32;   // seq tile
  int c0 = blockIdx.y * 32;   // channel tile (kv*128+d)
#pragma unroll
  for (int i = 0; i < 4; i++)
    tile[ty + i * 8][tx] = qkv[(size_t)(t0 + ty + i * 8) * QKVN + 5120 + c0 + tx];
  __syncthreads();
#pragma unroll
  for (int i = 0; i < 4; i++)
    vT[(size_t)(c0 + ty + i * 8) * TSEQ + t0 + tx] = tile[tx][ty + i * 8];
}

// ============ QKV GEMM: 256x192 tile, 3 phases x 16 MFMA (r9-benched, 123us) ============
// Staged issue: P1 stages A0-3(t+1), P2 stages B0,B1(t+1), P3 stages B2(t+1).
// Gates: P1-end vmcnt(4) (last tile: 0); P3-end vmcnt(1).
__global__ __launch_bounds__(512, 2) void k_gemmN192(const bf16_t* __restrict__ A,
                                                     const bf16_t* __restrict__ Bt,
                                                     bf16_t* __restrict__ Cout,
                                                     int M, int N, int K) {
  __shared__ bf16_t sA[2 * 256 * 64];    // 64 KB
  __shared__ bf16_t sB[2 * 192 * 64];    // 48 KB
  const int tid = threadIdx.x;
  const int lane = tid & 63, wave = tid >> 6;
  const int l15 = lane & 15, lhi = lane >> 4, l7 = l15 & 7;
  const int wr = wave >> 2, wc = wave & 3;
  const int wr128 = wr * 128, wc48 = wc * 48;
  const int bm = blockIdx.y * 256, bn = blockIdx.x * 192;
  const int nkt = K >> 6;

  const int r8 = tid >> 3;
  const int c16 = (tid & 7) ^ (r8 & 7);      // source pre-swizzle (T2)
  const bf16_t* Ag = A + (size_t)(bm + r8) * K + c16 * 8;
  const bf16_t* Bg = Bt + (size_t)(bn + r8) * K + c16 * 8;
  char* sAb = (char*)sA + wave * 1024;
  char* sBb = (char*)sB + wave * 1024;

#define STAGE_A(dst, bkk, r)                                                   \
  GLOAD_LDS16(Ag + (size_t)((r) * 64) * K + (bkk),                             \
              sAb + (dst) * 32768 + (r) * 8192)
#define STAGE_B(dst, bkk, q)                                                   \
  GLOAD_LDS16(Bg + (size_t)((q) * 64) * K + (bkk),                             \
              sBb + (dst) * 24576 + (q) * 8192)
#define RD_A(m, ks) (*(const bf16x8*)&sA[dofsA + ((wr128 + (m) * 16 + l15) << 6) + \
                                         ((((ks) * 4 + lhi) ^ l7) << 3)])
#define RD_B(n, ks) (*(const bf16x8*)&sB[dofsB + ((wc48 + (n) * 16 + l15) << 6) +  \
                                         ((((ks) * 4 + lhi) ^ l7) << 3)])

  f32x4 acc[8][3] = {};
  bf16x8 afL[4][2], afH[4][2], bf0[2], bf1[2], bf2[2];

  // prologue: stage tile 0 (order A0-3, B0-2); wait all but B2
  STAGE_A(0, 0, 0); STAGE_A(0, 0, 1); STAGE_A(0, 0, 2); STAGE_A(0, 0, 3);
  STAGE_B(0, 0, 0); STAGE_B(0, 0, 1); STAGE_B(0, 0, 2);
  asm volatile("s_waitcnt vmcnt(1)" ::: "memory");
  __builtin_amdgcn_s_barrier();

  for (int t = 0; t < nkt; ++t) {
    const int d = t & 1, dn = d ^ 1;
    const int dofsA = d * 16384;
    const int dofsB = d * 12288;
    const int bk1 = (t + 1) << 6;
    const bool pf = (t + 1 < nkt);

    // ---------- P1: read A-lo + B0,B1; stage A(t+1); MFMA lo x {B0,B1} ----------
#pragma unroll
    for (int m = 0; m < 4; m++)
#pragma unroll
      for (int ks = 0; ks < 2; ks++) afL[m][ks] = RD_A(m, ks);
#pragma unroll
    for (int ks = 0; ks < 2; ks++) { bf0[ks] = RD_B(0, ks); bf1[ks] = RD_B(1, ks); }
    if (pf) { STAGE_A(dn, bk1, 0); STAGE_A(dn, bk1, 1); STAGE_A(dn, bk1, 2); STAGE_A(dn, bk1, 3); }
    __builtin_amdgcn_s_barrier();
    asm volatile("s_waitcnt lgkmcnt(0)" ::: "memory");
    __builtin_amdgcn_sched_barrier(0);
    __builtin_amdgcn_s_setprio(1);
#pragma unroll
    for (int m = 0; m < 4; m++)
#pragma unroll
      for (int ks = 0; ks < 2; ks++) {
        acc[m][0] = __builtin_amdgcn_mfma_f32_16x16x32_bf16(afL[m][ks], bf0[ks], acc[m][0], 0, 0, 0);
        acc[m][1] = __builtin_amdgcn_mfma_f32_16x16x32_bf16(afL[m][ks], bf1[ks], acc[m][1], 0, 0, 0);
      }
    __builtin_amdgcn_s_setprio(0);
    if (pf) asm volatile("s_waitcnt vmcnt(4)" ::: "memory");  // B2(t) landed
    else    asm volatile("s_waitcnt vmcnt(0)" ::: "memory");
    __builtin_amdgcn_s_barrier();

    // ---------- P2: read A-hi + B2; stage B0,B1(t+1); MFMA loxB2 + hixB0 ----------
#pragma unroll
    for (int m = 0; m < 4; m++)
#pragma unroll
      for (int ks = 0; ks < 2; ks++) afH[m][ks] = RD_A(4 + m, ks);
#pragma unroll
    for (int ks = 0; ks < 2; ks++) bf2[ks] = RD_B(2, ks);
    if (pf) { STAGE_B(dn, bk1, 0); STAGE_B(dn, bk1, 1); }
    __builtin_amdgcn_s_barrier();
    asm volatile("s_waitcnt lgkmcnt(0)" ::: "memory");
    __builtin_amdgcn_sched_barrier(0);
    __builtin_amdgcn_s_setprio(1);
#pragma unroll
    for (int m = 0; m < 4; m++)
#pragma unroll
      for (int ks = 0; ks < 2; ks++) {
        acc[m][2] = __builtin_amdgcn_mfma_f32_16x16x32_bf16(afL[m][ks], bf2[ks], acc[m][2], 0, 0, 0);
        acc[4 + m][0] = __builtin_amdgcn_mfma_f32_16x16x32_bf16(afH[m][ks], bf0[ks], acc[4 + m][0], 0, 0, 0);
      }
    __builtin_amdgcn_s_setprio(0);
    __builtin_amdgcn_s_barrier();

    // ---------- P3: stage B2(t+1); MFMA hi x {B1,B2} ----------
    if (pf) STAGE_B(dn, bk1, 2);
    __builtin_amdgcn_s_setprio(1);
#pragma unroll
    for (int m = 0; m < 4; m++)
#pragma unroll
      for (int ks = 0; ks < 2; ks++) {
        acc[4 + m][1] = __builtin_amdgcn_mfma_f32_16x16x32_bf16(afH[m][ks], bf1[ks], acc[4 + m][1], 0, 0, 0);
        acc[4 + m][2] = __builtin_amdgcn_mfma_f32_16x16x32_bf16(afH[m][ks], bf2[ks], acc[4 + m][2], 0, 0, 0);
      }
    __builtin_amdgcn_s_setprio(0);
    if (pf) asm volatile("s_waitcnt vmcnt(1)" ::: "memory");  // A0-3,B0,B1(t+1) landed
    __builtin_amdgcn_s_barrier();
  }
#undef STAGE_A
#undef STAGE_B
#undef RD_A
#undef RD_B

  // epilogue (C/D layout: col=lane&15, row=(lane>>4)*4+reg)
#pragma unroll
  for (int m = 0; m < 8; m++)
#pragma unroll
    for (int n = 0; n < 3; n++)
#pragma unroll
      for (int b = 0; b < 4; b++) {
        int row = bm + wr128 + m * 16 + lhi * 4 + b;
        int col = bn + wc48 + n * 16 + l15;
        Cout[(size_t)row * N + col] = (bf16_t)acc[m][n][b];
      }
}

// ========= O-proj GEMM: 128x256 tile, full K, triple-buffered deep ladder =========
// Grid 16x16 = 256 WGs (exact full fill) — replaces split-K + addout (which paid
// 2x prologue on K=2048 slices + 167 MB of partial traffic).
// 512 thr = 8 waves (2M x 4N): per-wave 64x64, acc[4][4]. 2 phases x 16 MFMA.
// LDS: 3 buffers x (A 16KB + B 32KB) = 144 KB. Loads for tile t+2 issued during
// tile t (P1: b0,b1,b2; P2: b3,a0,a1) -> the P2-end gate waits on loads issued a
// FULL TILE (4 phases) earlier: vmcnt(6) steady (t+2's 6 in flight), never 0
// except drain (t=nkt-2: vmcnt(0); t=nkt-1: none).
// WAR: buffer (t+2)%3 last read in tile t-1, sealed by its lgkmcnt(0)+barrier
// before P1(t) issues into it.
__global__ __launch_bounds__(512, 2) void k_gemm128x256(const bf16_t* __restrict__ A,
                                                        const bf16_t* __restrict__ Bt,
                                                        float* __restrict__ C,
                                                        int M, int N, int K) {
  __shared__ bf16_t sA[3 * 128 * 64];   // 48 KB
  __shared__ bf16_t sB[3 * 256 * 64];   // 96 KB
  const int tid = threadIdx.x;
  const int lane = tid & 63, wave = tid >> 6;
  const int l15 = lane & 15, lhi = lane >> 4, l7 = l15 & 7;
  const int wr = wave >> 2, wc = wave & 3;
  const int wr64 = wr * 64, wc64 = wc * 64;
  const int bm = blockIdx.y * 128, bn = blockIdx.x * 256;
  const int nkt = K >> 6;

  const int r8 = tid >> 3;                   // 0..63: row within 64-row chunk
  const int c16 = (tid & 7) ^ (r8 & 7);      // source pre-swizzle (T2)
  const bf16_t* Ag = A + (size_t)(bm + r8) * K + c16 * 8;
  const bf16_t* Bg = Bt + (size_t)(bn + r8) * K + c16 * 8;
  char* sAb = (char*)sA + wave * 1024;       // wave-uniform LDS bases
  char* sBb = (char*)sB + wave * 1024;

#define OSTG_A(dbuf, bkk, c)                                                   \
  GLOAD_LDS16(Ag + (size_t)((c) * 64) * K + (bkk),                             \
              sAb + (dbuf) * 16384 + (c) * 8192)
#define OSTG_B(dbuf, bkk, c)                                                   \
  GLOAD_LDS16(Bg + (size_t)((c) * 64) * K + (bkk),                             \
              sBb + (dbuf) * 32768 + (c) * 8192)
#define ORD_A(m, ks) (*(const bf16x8*)&sA[dofsA + ((wr64 + (m) * 16 + l15) << 6) + \
                                          ((((ks) * 4 + lhi) ^ l7) << 3)])
#define ORD_B(n, ks) (*(const bf16x8*)&sB[dofsB + ((wc64 + (n) * 16 + l15) << 6) + \
                                          ((((ks) * 4 + lhi) ^ l7) << 3)])

  f32x4 acc[4][4] = {};
  bf16x8 af[4][2], bfr[4][2];

  // prologue: tile 0 -> buf0, tile 1 -> buf1 (6 loads each)
  OSTG_B(0, 0, 0); OSTG_B(0, 0, 1); OSTG_B(0, 0, 2); OSTG_B(0, 0, 3);
  OSTG_A(0, 0, 0); OSTG_A(0, 0, 1);
  OSTG_B(1, 64, 0); OSTG_B(1, 64, 1); OSTG_B(1, 64, 2); OSTG_B(1, 64, 3);
  OSTG_A(1, 64, 0); OSTG_A(1, 64, 1);
  asm volatile("s_waitcnt vmcnt(6)" ::: "memory");   // tile 0 landed
  __builtin_amdgcn_s_barrier();

  int d = 0, d2 = 2;
  for (int t = 0; t < nkt; ++t) {
    const int dofsA = d * 8192;           // element offsets of current buffer
    const int dofsB = d * 16384;
    const int bk2 = (t + 2) << 6;
    const bool pf2 = (t + 2 < nkt);

    // ---------- P1: read A(all 4) + B n0,n1; issue b0,b1,b2 (t+2); MFMA m x n01 ----------
#pragma unroll
    for (int m = 0; m < 4; m++)
#pragma unroll
      for (int ks = 0; ks < 2; ks++) af[m][ks] = ORD_A(m, ks);
#pragma unroll
    for (int n = 0; n < 2; n++)
#pragma unroll
      for (int ks = 0; ks < 2; ks++) bfr[n][ks] = ORD_B(n, ks);
    if (pf2) { OSTG_B(d2, bk2, 0); OSTG_B(d2, bk2, 1); OSTG_B(d2, bk2, 2); }
    __builtin_amdgcn_s_barrier();
    asm volatile("s_waitcnt lgkmcnt(0)" ::: "memory");
    __builtin_amdgcn_sched_barrier(0);
    __builtin_amdgcn_s_setprio(1);
#pragma unroll
    for (int m = 0; m < 4; m++)
#pragma unroll
      for (int n = 0; n < 2; n++)
#pragma unroll
        for (int ks = 0; ks < 2; ks++)
          acc[m][n] = __builtin_amdgcn_mfma_f32_16x16x32_bf16(af[m][ks], bfr[n][ks], acc[m][n], 0, 0, 0);
    __builtin_amdgcn_s_setprio(0);
    __builtin_amdgcn_s_barrier();

    // ---------- P2: read B n2,n3; issue b3,a0,a1 (t+2); MFMA m x n23; gate ----------
#pragma unroll
    for (int n = 0; n < 2; n++)
#pragma unroll
      for (int ks = 0; ks < 2; ks++) bfr[2 + n][ks] = ORD_B(2 + n, ks);
    if (pf2) { OSTG_B(d2, bk2, 3); OSTG_A(d2, bk2, 0); OSTG_A(d2, bk2, 1); }
    __builtin_amdgcn_s_barrier();
    asm volatile("s_waitcnt lgkmcnt(0)" ::: "memory");
    __builtin_amdgcn_sched_barrier(0);
    __builtin_amdgcn_s_setprio(1);
#pragma unroll
    for (int m = 0; m < 4; m++)
#pragma unroll
      for (int n = 0; n < 2; n++)
#pragma unroll
        for (int ks = 0; ks < 2; ks++)
          acc[m][2 + n] = __builtin_amdgcn_mfma_f32_16x16x32_bf16(af[m][ks], bfr[2 + n][ks], acc[m][2 + n], 0, 0, 0);
    __builtin_amdgcn_s_setprio(0);
    // gate: tile t+1 fully landed (its 6 loads were issued during t-1, 4 phases back)
    if (pf2)               asm volatile("s_waitcnt vmcnt(6)" ::: "memory");
    else if (t + 1 < nkt)  asm volatile("s_waitcnt vmcnt(0)" ::: "memory");
    __builtin_amdgcn_s_barrier();

    d  = (d  == 2) ? 0 : d + 1;
    d2 = (d2 == 2) ? 0 : d2 + 1;
  }
#undef OSTG_A
#undef OSTG_B
#undef ORD_A
#undef ORD_B

  // epilogue: f32 C write (C/D layout: col=lane&15, row=(lane>>4)*4+reg)
#pragma unroll
  for (int m = 0; m < 4; m++)
#pragma unroll
    for (int n = 0; n < 4; n++)
#pragma unroll
      for (int b = 0; b < 4; b++) {
        int row = bm + wr64 + m * 16 + lhi * 4 + b;
        int col = bn + wc64 + n * 16 + l15;
        C[(size_t)row * N + col] = acc[m][n][b];
      }
}

// ---------------- Flash attention v3 + T5 setprio (causal, GQA) ----------------
__global__ __launch_bounds__(512, 2) void k_flash(const bf16_t* __restrict__ qkv,
                                                  const bf16_t* __restrict__ vT,
                                                  bf16_t* __restrict__ attn) {
  __shared__ bf16_t Kl[64][152];   // [s][d] pad 152
  __shared__ bf16_t Vl[128][88];   // [d][s] pad 88
  __shared__ bf16_t Pl[128][88];   // [t][s] pad 88
  const int h = blockIdx.x;
  const int by = blockIdx.y;
  const int qt = (by < 8) ? by : 23 - by;   // zig-zag: CU pair work sums const
  const int kvh = h >> 2;
  const int tid = threadIdx.x, lane = tid & 63, wave = tid >> 6;
  const int l15 = lane & 15, lhi = lane >> 4;
  const int qbase = qt * 128, wrow = wave * 16;

  bf16x8 qf[4];
#pragma unroll
  for (int ks = 0; ks < 4; ks++)
    qf[ks] = *(const bf16x8*)&qkv[(size_t)(qbase + wrow + l15) * QKVN +
                                  h * 128 + ks * 32 + lhi * 8];

  f32x4 o[8] = {};
  float m_i[4], l_i[4];
#pragma unroll
  for (int b = 0; b < 4; b++) { m_i[b] = -1e30f; l_i[b] = 0.f; }

  const int ks0 = tid >> 4, kd0 = (tid & 15) * 8;          // K rows 0..31 / 32..63
  const int vd0 = tid >> 3, vs0 = (tid & 7) * 8;           // V rows 0..63 / 64..127
  const bf16_t* Kg = qkv + 4096 + (size_t)kvh * 128;
  const bf16_t* Vg = vT + (size_t)(kvh * 128) * TSEQ;

  float4 rk0, rk1, rv0, rv1;   // buffer A
  float4 sk0, sk1, sv0, sv1;   // buffer B

#define LOADKV(a, b, c, d, ktl)                                                 \
  do {                                                                          \
    a = *(const float4*)&Kg[(size_t)((ktl) * 64 + ks0) * QKVN + kd0];           \
    b = *(const float4*)&Kg[(size_t)((ktl) * 64 + 32 + ks0) * QKVN + kd0];      \
    c = *(const float4*)&Vg[(size_t)vd0 * TSEQ + (ktl) * 64 + vs0];             \
    d = *(const float4*)&Vg[(size_t)(64 + vd0) * TSEQ + (ktl) * 64 + vs0];      \
  } while (0)

#define WRITEKV(a, b, c, d)                                                     \
  do {                                                                          \
    *(float4*)&Kl[ks0][kd0] = a;                                                \
    *(float4*)&Kl[32 + ks0][kd0] = b;                                           \
    *(float4*)&Vl[vd0][vs0] = c;                                                \
    *(float4*)&Vl[64 + vd0][vs0] = d;                                           \
  } while (0)

  const int ktmax = qt * 2 + 1;   // always odd -> even iteration count
  LOADKV(rk0, rk1, rv0, rv1, 0);

  for (int kt = 0; kt <= ktmax; kt += 2) {
#pragma unroll
    for (int sub = 0; sub < 2; ++sub) {
      const int ktc = kt + sub;
      __syncthreads();
      if (sub == 0) {
        WRITEKV(rk0, rk1, rv0, rv1);
        LOADKV(sk0, sk1, sv0, sv1, kt + 1);
      } else {
        WRITEKV(sk0, sk1, sv0, sv1);
        if (kt + 2 <= ktmax) LOADKV(rk0, rk1, rv0, rv1, kt + 2);
      }
      __syncthreads();

      f32x4 sa[4] = {};
      __builtin_amdgcn_s_setprio(1);   // T5: QK^T cluster
#pragma unroll
      for (int ks = 0; ks < 4; ks++) {
        bf16x8 kb[4];
#pragma unroll
        for (int j = 0; j < 4; j++)
          kb[j] = *(const bf16x8*)&Kl[j * 16 + l15][ks * 32 + lhi * 8];
#pragma unroll
        for (int j = 0; j < 4; j++)
          sa[j] = __builtin_amdgcn_mfma_f32_16x16x32_bf16(qf[ks], kb[j], sa[j], 0, 0, 0);
      }
      __builtin_amdgcn_s_setprio(0);
#pragma unroll
      for (int b = 0; b < 4; b++) {
        int trow = qbase + wrow + lhi * 4 + b;
        float mx = -1e30f;
#pragma unroll
        for (int j = 0; j < 4; j++) {
          int scol = ktc * 64 + j * 16 + l15;
          if (scol > trow) sa[j][b] = -1e30f;
          mx = fmaxf(mx, sa[j][b]);
        }
#pragma unroll
        for (int off = 1; off < 16; off <<= 1) mx = fmaxf(mx, __shfl_xor(mx, off));
        float mn = fmaxf(m_i[b], mx);
        float corr = __expf(m_i[b] - mn);
        float sum = 0.f;
#pragma unroll
        for (int j = 0; j < 4; j++) {
          float pv = __expf(sa[j][b] - mn);
          sa[j][b] = pv;
          sum += pv;
        }
#pragma unroll
        for (int off = 1; off < 16; off <<= 1) sum += __shfl_xor(sum, off);
        l_i[b] = l_i[b] * corr + sum;
        m_i[b] = mn;
#pragma unroll
        for (int j = 0; j < 8; j++) o[j][b] *= corr;
#pragma unroll
        for (int j = 0; j < 4; j++)
          Pl[wrow + lhi * 4 + b][j * 16 + l15] = (bf16_t)sa[j][b];
      }
      __builtin_amdgcn_s_setprio(1);   // T5: PV cluster
#pragma unroll
      for (int ks = 0; ks < 2; ks++) {
        bf16x8 pa = *(const bf16x8*)&Pl[wrow + l15][ks * 32 + lhi * 8];
#pragma unroll
        for (int j = 0; j < 8; j++) {
          bf16x8 vb = *(const bf16x8*)&Vl[j * 16 + l15][ks * 32 + lhi * 8];
          o[j] = __builtin_amdgcn_mfma_f32_16x16x32_bf16(pa, vb, o[j], 0, 0, 0);
        }
      }
      __builtin_amdgcn_s_setprio(0);
      __syncthreads();
    }
  }
#undef LOADKV
#undef WRITEKV

#pragma unroll
  for (int j = 0; j < 8; j++)
#pragma unroll
    for (int b = 0; b < 4; b++) {
      int trow = qbase + wrow + lhi * 4 + b;
      attn[(size_t)trow * (NH * HD) + h * 128 + j * 16 + l15] =
          (bf16_t)(o[j][b] / l_i[b]);
    }
}

// ---------------- launcher ----------------
extern "C" void kernel_launch(void* const* d_in, const int* in_sizes, int n_in,
                              void* d_out, int out_size, void* d_ws, size_t ws_size,
                              hipStream_t stream) {
  const int* positions = (const int*)d_in[0];
  const float* hs = (const float*)d_in[1];
  const float* wqkv = (const float*)d_in[2];
  const float* wo = (const float*)d_in[3];
  float* out = (float*)d_out;

  char* ws = (char*)d_ws;
  bf16_t* hsb   = (bf16_t*)(ws);                       // 16.78 MB (-> attn later)
  bf16_t* wqkvT = (bf16_t*)(ws + 16777216);            // 50.33 MB
  bf16_t* woT   = (bf16_t*)(ws + 67108864);            // 33.55 MB
  bf16_t* qkv   = (bf16_t*)(ws + 100663296);           // 25.17 MB
  bf16_t* vT    = (bf16_t*)(ws + 125829120);           //  4.19 MB
  bf16_t* attn  = hsb;                                 // reuse (hsb dead after GEMM1)

  // 1. convert hidden_states
  k_f32_to_bf16<<<(TSEQ * HID / 4 + 255) / 256, 256, 0, stream>>>(hs, hsb, TSEQ * HID);
  // 2. transpose-convert weights to [N][K] (64x64 vectorized tiles)
  k_transpose64<<<dim3(QKVN / 64, HID / 64), 256, 0, stream>>>(wqkv, wqkvT, HID, QKVN);
  k_transpose64<<<dim3(HID / 64, (NH * HD) / 64), 256, 0, stream>>>(wo, woT, NH * HD, HID);
  // 3. QKV projection (256x192 tiles, staged 3-phase, 32x8 = 256 WGs)
  k_gemmN192<<<dim3(QKVN / 192, TSEQ / 256), 512, 0, stream>>>(hsb, wqkvT, qkv, TSEQ, QKVN, HID);
  // 4. RoPE in place (q scaled)
  k_rope<<<dim3(10, TSEQ), 256, 0, stream>>>(qkv, positions);
  // 5. transpose V -> vT [1024][T]
  k_transpose_v<<<dim3(TSEQ / 32, 1024 / 32), 256, 0, stream>>>(qkv, vT);
  // 6. flash attention -> attn bf16 [T][4096]
  k_flash<<<dim3(NH, 16), 512, 0, stream>>>(qkv, vT, attn);
  // 7. output projection: 128x256 tiles, full K, 16x16 = 256 WGs (no split-K)
  k_gemm128x256<<<dim3(HID / 256, TSEQ / 128), 512, 0, stream>>>(attn, woT, out, TSEQ, HID, HID);
}